// Round 8
// baseline (412.416 us; speedup 1.0000x reference)
//
#include <hip/hip_runtime.h>
#include <math.h>

// Problem constants
#define BATCH 2
#define C3 256
#define C2 128
#define C1 64
#define HH 48
#define WW 48
#define L 2304          // 48*48 unfold positions
#define GK 256          // channel dim for G-GEMM
#define BK2 64          // K-tile (bf16) for G-GEMM
#define NSEG 16
#define SEG 144         // 2304/16

// Output flat offsets (float elements)
#define OFF_T3 13824
#define OFF_T2 3552768
#define OFF_T1 10630656

typedef __bf16 bf16x8 __attribute__((ext_vector_type(8)));
typedef float  f32x4  __attribute__((ext_vector_type(4)));
typedef float  f32x2  __attribute__((ext_vector_type(2)));
typedef int    i32x4  __attribute__((ext_vector_type(4)));
// dword-aligned (not 16B) float4 for shifted stencil loads
typedef float  f32x4u __attribute__((ext_vector_type(4), aligned(4)));

__device__ __forceinline__ void gload16(const void* g, void* l) {
    __builtin_amdgcn_global_load_lds(
        (const __attribute__((address_space(1))) void*)g,
        (__attribute__((address_space(3))) void*)l, 16, 0, 0);
}

__device__ __forceinline__ void nts4(float* p, float a, float b, float c, float d) {
    f32x4 v = {a, b, c, d};
    __builtin_nontemporal_store(v, (f32x4*)p);
}
__device__ __forceinline__ void nts2(float* p, float a, float b) {
    f32x2 v = {a, b};
    __builtin_nontemporal_store(v, (f32x2*)p);
}

// ---------------- per-pixel channel sum of squares, 4-way channel split ----------------
__global__ void ssq_kernel(const float* __restrict__ lr, const float* __restrict__ refsr,
                           float* __restrict__ ssQ4, float* __restrict__ ssK4) {
    int idx = blockIdx.x * 256 + threadIdx.x;
    if (idx >= BATCH * L) return;
    int img_i = blockIdx.y & 1, seg = blockIdx.y >> 1;
    const float* img = img_i ? refsr : lr;
    float* ss = (img_i ? ssK4 : ssQ4) + seg * (BATCH * L);
    int b = idx / L, yx = idx % L;
    const float* p = img + ((size_t)b * C3 + seg * 64) * L + yx;
    float s = 0.f;
    #pragma unroll 4
    for (int c = 0; c < 64; ++c) { float v = p[(size_t)c * L]; s += v * v; }
    ss[idx] = s;
}

// ---------------- 3x3 window sum over 4 partials -> 1/max(sqrt, eps) (both) ----------------
__global__ void norm_kernel(const float* __restrict__ ssQ4, const float* __restrict__ ssK4,
                            float* __restrict__ rnQ, float* __restrict__ rnK) {
    int idx = blockIdx.x * 256 + threadIdx.x;
    if (idx >= BATCH * L) return;
    const float* ss = blockIdx.y ? ssK4 : ssQ4;
    float* rn = blockIdx.y ? rnK : rnQ;
    int b = idx / L, l = idx % L;
    int ly = l / WW, lx = l % WW;
    const float* s = ss + b * L;
    float acc = 0.f;
    #pragma unroll
    for (int dy = -1; dy <= 1; ++dy) {
        int yy = ly + dy;
        if ((unsigned)yy >= (unsigned)HH) continue;
        #pragma unroll
        for (int dx = -1; dx <= 1; ++dx) {
            int xx = lx + dx;
            if ((unsigned)xx >= (unsigned)WW) continue;
            int o = yy * WW + xx;
            acc += s[o] + s[BATCH * L + o] + s[2 * BATCH * L + o] + s[3 * BATCH * L + o];
        }
    }
    float n = sqrtf(acc);
    n = fmaxf(n, 1e-12f);
    rn[idx] = 1.0f / n;
}

// ---------------- transpose [C][pix] -> [pix][C] + bf16 hi/lo split (both images) ----
__global__ __launch_bounds__(256) void split_t(const float* __restrict__ lr,
                                               const float* __restrict__ refsr,
                                               __bf16* __restrict__ Qhi, __bf16* __restrict__ Qlo,
                                               __bf16* __restrict__ Khi, __bf16* __restrict__ Klo) {
    __shared__ float tile[64][65];
    int bz = blockIdx.z;
    int b = bz >> 1;
    const float* img = (bz & 1) ? refsr : lr;
    __bf16* dh = (bz & 1) ? Khi : Qhi;
    __bf16* dl = (bz & 1) ? Klo : Qlo;
    int u0 = blockIdx.x * 64, c0 = blockIdx.y * 64;
    int t = threadIdx.x;
    {
        int ul = t & 63, cl0 = t >> 6;
        const float* src = img + ((size_t)b * C3 + c0) * L + u0;
        #pragma unroll
        for (int r = 0; r < 16; ++r) {
            int cl = cl0 + r * 4;
            tile[cl][ul] = src[(size_t)cl * L + ul];
        }
    }
    __syncthreads();
    {
        int cl = t & 63, ul0 = t >> 6;
        __bf16* oh = dh + ((size_t)b * L + u0) * GK + c0 + cl;
        __bf16* ol = dl + ((size_t)b * L + u0) * GK + c0 + cl;
        #pragma unroll
        for (int r = 0; r < 16; ++r) {
            int ul = ul0 + r * 4;
            float v = tile[cl][ul];
            __bf16 h = (__bf16)v;
            float lo = v - (float)h;
            oh[(size_t)ul * GK] = h;
            ol[(size_t)ul * GK] = (__bf16)lo;
        }
    }
}

// ---------------- split-bf16 MFMA GEMM NT over K=256: G[u,v] ----------------
__global__ __launch_bounds__(256) void gemm_g(const __bf16* __restrict__ Khi,
                                              const __bf16* __restrict__ Klo,
                                              const __bf16* __restrict__ Qhi,
                                              const __bf16* __restrict__ Qlo,
                                              float* __restrict__ Gg) {
    __shared__ __align__(16) __bf16 Ah[64 * BK2];
    __shared__ __align__(16) __bf16 Al[64 * BK2];
    __shared__ __align__(16) __bf16 Bh[128 * BK2];
    __shared__ __align__(16) __bf16 Bl[128 * BK2];
    int t = threadIdx.x;
    int lane = t & 63;
    int wv = t >> 6;
    int b = blockIdx.z;
    size_t ioff = (size_t)b * L * GK;
    const __bf16* Ahg = Khi + ioff;   // rows u (refsr)
    const __bf16* Alg = Klo + ioff;
    const __bf16* Bhg = Qhi + ioff;   // rows v (lr)
    const __bf16* Blg = Qlo + ioff;
    int m0 = blockIdx.x * 128;
    int l0 = blockIdx.y * 64;
    int wl = wv >> 1, wm = wv & 1;    // wave tile: 32(u) x 64(v)
    int q = lane >> 4, r16 = lane & 15;

    f32x4 acc[2][4];
    #pragma unroll
    for (int i = 0; i < 2; i++)
        #pragma unroll
        for (int j = 0; j < 4; j++) acc[i][j] = (f32x4)(0.f);

    for (int k0 = 0; k0 < GK; k0 += BK2) {
        #pragma unroll
        for (int hh = 0; hh < 2; ++hh) {          // A: 512 chunks of 16B
            int c = t + hh * 256;
            int row = c >> 3, qo = c & 7;
            size_t ga = (size_t)(l0 + row) * GK + k0 + ((qo ^ (row & 7)) * 8);
            gload16(Ahg + ga, &Ah[c * 8]);
            gload16(Alg + ga, &Al[c * 8]);
        }
        #pragma unroll
        for (int hh = 0; hh < 4; ++hh) {          // B: 1024 chunks
            int c = t + hh * 256;
            int row = c >> 3, qo = c & 7;
            size_t gb = (size_t)(m0 + row) * GK + k0 + ((qo ^ (row & 7)) * 8);
            gload16(Bhg + gb, &Bh[c * 8]);
            gload16(Blg + gb, &Bl[c * 8]);
        }
        __syncthreads();

        #pragma unroll
        for (int h = 0; h < 2; ++h) {             // two k-32 halves of BK=64
            bf16x8 ah[2], al[2], bh[4], bl[4];
            #pragma unroll
            for (int i = 0; i < 2; ++i) {
                int row = wl * 32 + i * 16 + r16;
                int ch = (h * 4 + q) ^ (row & 7);
                ah[i] = *(const bf16x8*)&Ah[row * BK2 + ch * 8];
                al[i] = *(const bf16x8*)&Al[row * BK2 + ch * 8];
            }
            #pragma unroll
            for (int j = 0; j < 4; ++j) {
                int row = wm * 64 + j * 16 + r16;
                int ch = (h * 4 + q) ^ (row & 7);
                bh[j] = *(const bf16x8*)&Bh[row * BK2 + ch * 8];
                bl[j] = *(const bf16x8*)&Bl[row * BK2 + ch * 8];
            }
            #pragma unroll
            for (int i = 0; i < 2; ++i)
                #pragma unroll
                for (int j = 0; j < 4; ++j) {
                    acc[i][j] = __builtin_amdgcn_mfma_f32_16x16x32_bf16(ah[i], bh[j], acc[i][j], 0, 0, 0);
                    acc[i][j] = __builtin_amdgcn_mfma_f32_16x16x32_bf16(ah[i], bl[j], acc[i][j], 0, 0, 0);
                    acc[i][j] = __builtin_amdgcn_mfma_f32_16x16x32_bf16(al[i], bh[j], acc[i][j], 0, 0, 0);
                }
        }
        __syncthreads();
    }

    float* Cb = Gg + (size_t)b * L * L;
    #pragma unroll
    for (int i = 0; i < 2; ++i) {
        int rowb = l0 + wl * 32 + i * 16 + q * 4;
        #pragma unroll
        for (int j = 0; j < 4; ++j) {
            int col = m0 + wm * 64 + j * 16 + r16;
            #pragma unroll
            for (int r = 0; r < 4; ++r)
                Cb[(size_t)(rowb + r) * L + col] = acc[i][j][r];
        }
    }
}

// ---------------- R[l,m] = rnK[l]*rnQ[m]*sum_{9 diag shifts} G[l+s, m+s] ----------------
__global__ __launch_bounds__(576) void stencil_R(const float* __restrict__ G,
                                                 const float* __restrict__ rnK,
                                                 const float* __restrict__ rnQ,
                                                 float* __restrict__ R) {
    int blk = blockIdx.x;                 // 0..1151
    int xcd = blk & 7, idx = blk >> 3;    // 144 chunks per XCD
    int gc = xcd * 144 + idx;             // contiguous l-chunks per XCD
    int b = gc / 576;
    int lbase = (gc % 576) * 4;
    int m0 = threadIdx.x * 4;
    const float* Gb = G + (size_t)b * L * L;
    int mdiv0 = m0 / 48, mmod0 = m0 % 48; // 4 cols never straddle a 48-boundary
    const float* rq = rnQ + b * L + m0;
    float rqv0 = rq[0], rqv1 = rq[1], rqv2 = rq[2], rqv3 = rq[3];

    #pragma unroll
    for (int li = 0; li < 4; ++li) {
        int l = lbase + li;
        int ly = l / 48, lx = l % 48;
        float a0 = 0.f, a1 = 0.f, a2 = 0.f, a3 = 0.f;
        #pragma unroll
        for (int dy = -1; dy <= 1; ++dy) {
            if ((unsigned)(ly + dy) >= 48u) continue;
            if ((unsigned)(mdiv0 + dy) >= 48u) continue;    // uniform over the 4 cols
            #pragma unroll
            for (int dx = -1; dx <= 1; ++dx) {
                if ((unsigned)(lx + dx) >= 48u) continue;
                int s = dy * 48 + dx;
                f32x4u v = *(const f32x4u*)(Gb + (size_t)(l + s) * L + s + m0);
                bool e0 = (unsigned)(mmod0 + dx) < 48u;     // only j=0,dx=-1 can fail
                bool e3 = (unsigned)(mmod0 + 3 + dx) < 48u; // only j=3,dx=+1 can fail
                a0 += e0 ? v[0] : 0.f;
                a1 += v[1];
                a2 += v[2];
                a3 += e3 ? v[3] : 0.f;
            }
        }
        float rk = rnK[b * L + l];
        f32x4 o = { a0 * rk * rqv0, a1 * rk * rqv1, a2 * rk * rqv2, a3 * rk * rqv3 };
        *(f32x4*)(R + (size_t)b * L * L + (size_t)l * L + m0) = o;  // cached: re-read by argmax/top3
    }
}

// ---------------- segmented argmax over l (ties -> lowest l) ----------------
__global__ void argmax_part(const float* __restrict__ R, float* __restrict__ pv, int* __restrict__ pi) {
    int m = blockIdx.x * 256 + threadIdx.x;
    int seg = blockIdx.y, b = blockIdx.z;
    const float* Rb = R + (size_t)b * L * L;
    float bv = -3.4e38f; int bi = 0;
    int l0 = seg * SEG;
    #pragma unroll 4
    for (int j = 0; j < SEG; j++) {
        float v = Rb[(size_t)(l0 + j) * L + m];
        if (v > bv) { bv = v; bi = l0 + j; }
    }
    int o = (b * NSEG + seg) * L + m;
    pv[o] = bv; pi[o] = bi;
}

// ---------------- segmented top-3; fuses the argmax merge (hidx) in-block ----------------
__global__ void top3_part(const float* __restrict__ R, const float* __restrict__ apv,
                          const int* __restrict__ api,
                          float* __restrict__ pv, int* __restrict__ pr) {
    int m = blockIdx.x * 256 + threadIdx.x;
    int seg = blockIdx.y, b = blockIdx.z;
    const float* Rb = R + (size_t)b * L * L;
    __shared__ int hrow_s[SEG];
    if (threadIdx.x < SEG) {
        int l = seg * SEG + threadIdx.x;
        float bv = -3.4e38f; int bi = 0;
        #pragma unroll
        for (int s = 0; s < NSEG; s++) {
            int o = (b * NSEG + s) * L + l;
            float v = apv[o];
            if (v > bv) { bv = v; bi = api[o]; }
        }
        hrow_s[threadIdx.x] = bi;
    }
    __syncthreads();
    float v0 = -3.4e38f, v1 = -3.4e38f, v2 = -3.4e38f;
    int r0 = 0, r1 = 0, r2 = 0;
    #pragma unroll 4
    for (int j = 0; j < SEG; j++) {
        int row = hrow_s[j];
        float v = Rb[(size_t)row * L + m];
        if (v > v0)      { v2 = v1; r2 = r1; v1 = v0; r1 = r0; v0 = v; r0 = row; }
        else if (v > v1) { v2 = v1; r2 = r1; v1 = v;  r1 = row; }
        else if (v > v2) { v2 = v;  r2 = row; }
    }
    size_t o = ((size_t)(b * NSEG + seg) * 3) * L + m;
    pv[o] = v0; pv[o + L] = v1; pv[o + 2 * L] = v2;
    pr[o] = r0; pr[o + L] = r1; pr[o + 2 * L] = r2;
}

__global__ void top3_merge(const float* __restrict__ pv, const int* __restrict__ pr,
                           float* __restrict__ outS, int* __restrict__ effp) {
    int m = blockIdx.x * 256 + threadIdx.x;
    int b = blockIdx.y;
    float v0 = -3.4e38f, v1 = -3.4e38f, v2 = -3.4e38f;
    int r0 = 0, r1 = 0, r2 = 0;
    for (int s = 0; s < NSEG; s++) {
        size_t o = ((size_t)(b * NSEG + s) * 3) * L + m;
        #pragma unroll
        for (int j = 0; j < 3; j++) {
            float v = pv[o + (size_t)j * L];
            int r = pr[o + (size_t)j * L];
            if (v > v0)      { v2 = v1; r2 = r1; v1 = v0; r1 = r0; v0 = v; r0 = r; }
            else if (v > v1) { v2 = v1; r2 = r1; v1 = v;  r1 = r; }
            else if (v > v2) { v2 = v;  r2 = r; }
        }
    }
    outS[(0 * BATCH + b) * L + m] = v0;
    outS[(1 * BATCH + b) * L + m] = v1;
    outS[(2 * BATCH + b) * L + m] = v2;
    effp[(b * 3 + 0) * L + m] = ((r0 / 48) << 8) | (r0 % 48);
    effp[(b * 3 + 1) * L + m] = ((r1 / 48) << 8) | (r1 % 48);
    effp[(b * 3 + 2) * L + m] = ((r2 / 48) << 8) | (r2 % 48);
}

// ---------------- folds (all LDS-staged, all <= 46KB LDS) ----------------
// T1 row-split: output row r of a 4x4 quad accumulates ONLY row r of gathered
// patches, so block = one (plane, i, py): stage the 48x192 row-slice
// (rows == py mod 4) patch-major into 36.9KB LDS -- identical footprint and
// structure to the proven fold_t2_lds. Deletes t1prep and the giant-LDS variant.
__global__ __launch_bounds__(576) void fold_t1r(const float* __restrict__ ref, const int* __restrict__ effp,
                                                float* __restrict__ outT) {
    const int W = 192;
    __shared__ float sP[2304 * 4];         // 36.9 KB: row py of every 4x4 patch
    __shared__ int   sE[48 * 49];          // 9.2 KB ep table, stride 49
    int blk = blockIdx.x;                  // 1536 = 8 xcd * 192
    int xcd = blk & 7;
    int gc = xcd * 192 + (blk >> 3);       // contiguous chunks per XCD
    int py = gc & 3;
    int q = gc >> 2;                       // 0..383
    int i = q % 3, plane = q / 3;          // plane = b*64 + c
    int b = plane >> 6, c = plane & 63;
    int t = threadIdx.x;

    {   // stage row-slice: 4 coalesced f32x4 per thread (rows qy*4+py)
        const float* src = ref + (size_t)plane * (W * W);
        #pragma unroll
        for (int k = 0; k < 4; ++k) {
            int id = t + k * 576;          // 2304 chunks: qy*48 + qx
            int qy = id / 48, qx = id % 48;
            f32x4 v = *(const f32x4*)(src + (qy * 4 + py) * W + qx * 4);
            *(f32x4*)&sP[id * 4] = v;
        }
        const int* e = effp + (b * 3 + i) * L;
        i32x4 ev = *(const i32x4*)(e + t * 4);
        #pragma unroll
        for (int k = 0; k < 4; ++k) {
            int id = t * 4 + k;
            sE[(id / 48) * 49 + (id % 48)] = ev[k];
        }
    }
    __syncthreads();

    int y = t / 12, x0q = (t % 12) * 4;    // 4 x-adjacent quads per thread
    f32x4 acc[4];
    #pragma unroll
    for (int xi = 0; xi < 4; ++xi) acc[xi] = (f32x4)(0.f);
    #pragma unroll
    for (int dh = -1; dh <= 1; ++dh) {
        int ho = y + dh;
        if ((unsigned)ho >= 48u) continue;
        int ep6[6];
        #pragma unroll
        for (int j = 0; j < 6; ++j) {
            int wo = x0q - 1 + j;
            ep6[j] = ((unsigned)wo < 48u) ? sE[ho * 49 + wo] : -1;
        }
        #pragma unroll
        for (int xi = 0; xi < 4; ++xi) {
            #pragma unroll
            for (int dw = -1; dw <= 1; ++dw) {
                int ep = ep6[xi + dw + 1];
                if (ep < 0) continue;
                int yq = (ep >> 8) - dh, xq = (ep & 255) - dw;
                if ((unsigned)yq >= 48u || (unsigned)xq >= 48u) continue;
                acc[xi] += *(const f32x4*)&sP[(yq * 48 + xq) * 4];
            }
        }
    }
    const float k = 1.0f / 9.0f;
    float* dst = outT + (((size_t)i * BATCH + b) * C1 + c) * (size_t)(W * W) + (y * 4 + py) * W + x0q * 4;
    #pragma unroll
    for (int xi = 0; xi < 4; ++xi)
        nts4(dst + xi * 4, acc[xi][0] * k, acc[xi][1] * k, acc[xi][2] * k, acc[xi][3] * k);
}

// T2: LDS-staged (proven R5).
__global__ __launch_bounds__(576) void fold_t2_lds(const float* __restrict__ ref, const int* __restrict__ effp,
                                                   float* __restrict__ outT) {
    const int W = 96;
    __shared__ float sP[2304 * 4];         // 36.9 KB patch-major plane
    __shared__ int   sE[48 * 49];          // 9.4 KB ep table, stride 49
    int blk = blockIdx.x;                  // 768 = 8 xcd * 96
    int xcd = blk & 7;
    int gc = xcd * 96 + (blk >> 3);        // contiguous chunks per XCD
    int plane = gc / 3, i = gc % 3;        // plane = b*128 + c
    int b = plane >> 7, c = plane & 127;
    int t = threadIdx.x;

    {   // stage plane: 4 coalesced f32x4 per thread -> patch-major ds_write_b64 pairs
        const float* src = ref + (size_t)plane * (W * W);
        #pragma unroll
        for (int k = 0; k < 4; ++k) {
            int id = t + k * 576;          // f32x4 chunk id over the plane
            int row = id / 24, x4 = id % 24;
            f32x4 v = *(const f32x4*)(src + row * W + x4 * 4);
            int qy = row >> 1, py = row & 1;
            int base0 = (qy * 48 + 2 * x4) * 4 + py * 2;
            f32x2 lo = { v[0], v[1] }, hi = { v[2], v[3] };
            *(f32x2*)&sP[base0] = lo;
            *(f32x2*)&sP[base0 + 4] = hi;
        }
        const int* e = effp + (b * 3 + i) * L;
        i32x4 ev = *(const i32x4*)(e + t * 4);
        #pragma unroll
        for (int k = 0; k < 4; ++k) {
            int id = t * 4 + k;
            sE[(id / 48) * 49 + (id % 48)] = ev[k];
        }
    }
    __syncthreads();

    int y = t / 12, x0q = (t % 12) * 4;    // 4 x-adjacent quads per thread
    f32x4 acc[4];
    #pragma unroll
    for (int xi = 0; xi < 4; ++xi) acc[xi] = (f32x4)(0.f);
    #pragma unroll
    for (int dh = -1; dh <= 1; ++dh) {
        int ho = y + dh;
        if ((unsigned)ho >= 48u) continue;
        int ep6[6];
        #pragma unroll
        for (int j = 0; j < 6; ++j) {
            int wo = x0q - 1 + j;
            ep6[j] = ((unsigned)wo < 48u) ? sE[ho * 49 + wo] : -1;
        }
        #pragma unroll
        for (int xi = 0; xi < 4; ++xi) {
            #pragma unroll
            for (int dw = -1; dw <= 1; ++dw) {
                int ep = ep6[xi + dw + 1];
                if (ep < 0) continue;
                int yq = (ep >> 8) - dh, xq = (ep & 255) - dw;
                if ((unsigned)yq >= 48u || (unsigned)xq >= 48u) continue;
                acc[xi] += *(const f32x4*)&sP[(yq * 48 + xq) * 4];
            }
        }
    }
    const float k = 1.0f / 9.0f;
    float* dst = outT + (((size_t)i * BATCH + b) * C2 + c) * (size_t)(W * W) + (2 * y) * W + x0q * 2;
    nts4(dst,         acc[0][0] * k, acc[0][1] * k, acc[1][0] * k, acc[1][1] * k);
    nts4(dst + 4,     acc[2][0] * k, acc[2][1] * k, acc[3][0] * k, acc[3][1] * k);
    nts4(dst + W,     acc[0][2] * k, acc[0][3] * k, acc[1][2] * k, acc[1][3] * k);
    nts4(dst + W + 4, acc[2][2] * k, acc[2][3] * k, acc[3][2] * k, acc[3][3] * k);
}

// T3: LDS-staged gather (proven R4).
__global__ __launch_bounds__(576) void fold_t3_lds(const float* __restrict__ ref, const int* __restrict__ effp,
                                                   float* __restrict__ outT) {
    const int W = 48;
    __shared__ float sP[2304];
    __shared__ int   sE[48 * 49];          // stride 49: rotates banks per row
    int blk = blockIdx.x;                  // 1536 = 8 xcd * 192
    int xcd = blk & 7;
    int gc = xcd * 192 + (blk >> 3);       // contiguous plane-chunks per XCD
    int plane = gc / 3, i = gc % 3;        // plane = b*256 + c
    int b = plane >> 8, c = plane & 255;
    int t = threadIdx.x;

    {   // stage plane (one float4/thread) + ep table (one int4/thread, re-padded)
        const float* src = ref + (size_t)plane * (W * W);
        *(f32x4*)&sP[t * 4] = *(const f32x4*)(src + t * 4);
        const int* e = effp + (b * 3 + i) * L;
        i32x4 ev = *(const i32x4*)(e + t * 4);
        #pragma unroll
        for (int k = 0; k < 4; ++k) {
            int id = t * 4 + k;
            sE[(id / 48) * 49 + (id % 48)] = ev[k];
        }
    }
    __syncthreads();

    int y = t / 12, x0 = (t % 12) * 4;     // 576 threads cover 48x12 quads of 4 px
    float s0 = 0.f, s1 = 0.f, s2 = 0.f, s3 = 0.f;
    #pragma unroll
    for (int dh = -1; dh <= 1; ++dh) {
        int ho = y + dh;
        if ((unsigned)ho >= 48u) continue;
        int ep6[6];
        #pragma unroll
        for (int j = 0; j < 6; ++j) {
            int wo = x0 - 1 + j;
            ep6[j] = ((unsigned)wo < 48u) ? sE[ho * 49 + wo] : -1;
        }
        #pragma unroll
        for (int xi = 0; xi < 4; ++xi) {
            float acc = 0.f;
            #pragma unroll
            for (int dw = -1; dw <= 1; ++dw) {
                int ep = ep6[xi + dw + 1];
                if (ep < 0) continue;
                int yy = (ep >> 8) - dh, xx = (ep & 255) - dw;
                if ((unsigned)yy >= 48u || (unsigned)xx >= 48u) continue;
                acc += sP[yy * W + xx];
            }
            if (xi == 0) s0 += acc; else if (xi == 1) s1 += acc;
            else if (xi == 2) s2 += acc; else s3 += acc;
        }
    }
    const float k = 1.0f / 9.0f;
    nts4(outT + (((size_t)i * BATCH + b) * C3 + c) * (size_t)(W * W) + y * W + x0,
         s0 * k, s1 * k, s2 * k, s3 * k);
}

extern "C" void kernel_launch(void* const* d_in, const int* in_sizes, int n_in,
                              void* d_out, int out_size, void* d_ws, size_t ws_size,
                              hipStream_t stream) {
    const float* lr    = (const float*)d_in[0];
    const float* refsr = (const float*)d_in[1];
    const float* ref1  = (const float*)d_in[2];
    const float* ref2  = (const float*)d_in[3];
    const float* ref3  = (const float*)d_in[4];
    float* out = (float*)d_out;

    float*  R   = (float*)d_ws;                              // B*L*L fp32
    float*  G   = R + (size_t)BATCH * L * L;                 // B*L*L fp32
    __bf16* Khi = (__bf16*)(G + (size_t)BATCH * L * L);      // B*L*GK bf16 each
    __bf16* Klo = Khi + (size_t)BATCH * L * GK;
    __bf16* Qhi = Klo + (size_t)BATCH * L * GK;
    __bf16* Qlo = Qhi + (size_t)BATCH * L * GK;
    float* ssQ4 = (float*)(Qlo + (size_t)BATCH * L * GK);    // 4 * B*L
    float* ssK4 = ssQ4 + 4 * BATCH * L;
    float* rnQ = ssK4 + 4 * BATCH * L;
    float* rnK = rnQ + BATCH * L;
    float* apv = rnK + BATCH * L;
    float* pv  = apv + BATCH * NSEG * L;
    int*   api = (int*)(pv + (size_t)BATCH * NSEG * 3 * L);
    int*   pr  = api + BATCH * NSEG * L;
    int*   effp = pr + (size_t)BATCH * NSEG * 3 * L;

    ssq_kernel<<<dim3(18, 8), 256, 0, stream>>>(lr, refsr, ssQ4, ssK4);
    norm_kernel<<<dim3(18, 2), 256, 0, stream>>>(ssQ4, ssK4, rnQ, rnK);
    split_t<<<dim3(36, 4, BATCH * 2), 256, 0, stream>>>(lr, refsr, Qhi, Qlo, Khi, Klo);

    gemm_g<<<dim3(18, 36, BATCH), 256, 0, stream>>>(Khi, Klo, Qhi, Qlo, G);
    stencil_R<<<1152, 576, 0, stream>>>(G, rnK, rnQ, R);

    argmax_part<<<dim3(9, NSEG, BATCH), 256, 0, stream>>>(R, apv, api);
    top3_part<<<dim3(9, NSEG, BATCH), 256, 0, stream>>>(R, apv, api, pv, pr);
    top3_merge<<<dim3(9, BATCH), 256, 0, stream>>>(pv, pr, out, effp);

    fold_t3_lds<<<1536, 576, 0, stream>>>(ref3, effp, out + OFF_T3);
    fold_t2_lds<<<768,  576, 0, stream>>>(ref2, effp, out + OFF_T2);
    fold_t1r<<<1536, 576, 0, stream>>>(ref1, effp, out + OFF_T1);
}

// Round 9
// 351.278 us; speedup vs baseline: 1.1740x; 1.1740x over previous
//
#include <hip/hip_runtime.h>
#include <math.h>

// Problem constants
#define BATCH 2
#define C3 256
#define C2 128
#define C1 64
#define HH 48
#define WW 48
#define L 2304          // 48*48 unfold positions
#define GK 256          // channel dim for G-GEMM
#define BK2 64          // K-tile (bf16) for G-GEMM
#define NSEG 16
#define SEG 144         // 2304/16

// Output flat offsets (float elements)
#define OFF_T3 13824
#define OFF_T2 3552768
#define OFF_T1 10630656

typedef __bf16 bf16x8 __attribute__((ext_vector_type(8)));
typedef float  f32x4  __attribute__((ext_vector_type(4)));
typedef float  f32x2  __attribute__((ext_vector_type(2)));
typedef int    i32x4  __attribute__((ext_vector_type(4)));
// dword-aligned (not 16B) float4 for shifted stencil loads
typedef float  f32x4u __attribute__((ext_vector_type(4), aligned(4)));

__device__ __forceinline__ void gload16(const void* g, void* l) {
    __builtin_amdgcn_global_load_lds(
        (const __attribute__((address_space(1))) void*)g,
        (__attribute__((address_space(3))) void*)l, 16, 0, 0);
}

__device__ __forceinline__ void nts4(float* p, float a, float b, float c, float d) {
    f32x4 v = {a, b, c, d};
    __builtin_nontemporal_store(v, (f32x4*)p);
}
__device__ __forceinline__ void nts2(float* p, float a, float b) {
    f32x2 v = {a, b};
    __builtin_nontemporal_store(v, (f32x2*)p);
}

// ---------------- per-pixel channel sum of squares, 4-way channel split ----------------
__global__ void ssq_kernel(const float* __restrict__ lr, const float* __restrict__ refsr,
                           float* __restrict__ ssQ4, float* __restrict__ ssK4) {
    int idx = blockIdx.x * 256 + threadIdx.x;
    if (idx >= BATCH * L) return;
    int img_i = blockIdx.y & 1, seg = blockIdx.y >> 1;
    const float* img = img_i ? refsr : lr;
    float* ss = (img_i ? ssK4 : ssQ4) + seg * (BATCH * L);
    int b = idx / L, yx = idx % L;
    const float* p = img + ((size_t)b * C3 + seg * 64) * L + yx;
    float s = 0.f;
    #pragma unroll 4
    for (int c = 0; c < 64; ++c) { float v = p[(size_t)c * L]; s += v * v; }
    ss[idx] = s;
}

// ---------------- 3x3 window sum over 4 partials -> 1/max(sqrt, eps) (both) ----------------
__global__ void norm_kernel(const float* __restrict__ ssQ4, const float* __restrict__ ssK4,
                            float* __restrict__ rnQ, float* __restrict__ rnK) {
    int idx = blockIdx.x * 256 + threadIdx.x;
    if (idx >= BATCH * L) return;
    const float* ss = blockIdx.y ? ssK4 : ssQ4;
    float* rn = blockIdx.y ? rnK : rnQ;
    int b = idx / L, l = idx % L;
    int ly = l / WW, lx = l % WW;
    const float* s = ss + b * L;
    float acc = 0.f;
    #pragma unroll
    for (int dy = -1; dy <= 1; ++dy) {
        int yy = ly + dy;
        if ((unsigned)yy >= (unsigned)HH) continue;
        #pragma unroll
        for (int dx = -1; dx <= 1; ++dx) {
            int xx = lx + dx;
            if ((unsigned)xx >= (unsigned)WW) continue;
            int o = yy * WW + xx;
            acc += s[o] + s[BATCH * L + o] + s[2 * BATCH * L + o] + s[3 * BATCH * L + o];
        }
    }
    float n = sqrtf(acc);
    n = fmaxf(n, 1e-12f);
    rn[idx] = 1.0f / n;
}

// ---------------- transpose [C][pix] -> [pix][C] + bf16 hi/lo split (both images) ----
__global__ __launch_bounds__(256) void split_t(const float* __restrict__ lr,
                                               const float* __restrict__ refsr,
                                               __bf16* __restrict__ Qhi, __bf16* __restrict__ Qlo,
                                               __bf16* __restrict__ Khi, __bf16* __restrict__ Klo) {
    __shared__ float tile[64][65];
    int bz = blockIdx.z;
    int b = bz >> 1;
    const float* img = (bz & 1) ? refsr : lr;
    __bf16* dh = (bz & 1) ? Khi : Qhi;
    __bf16* dl = (bz & 1) ? Klo : Qlo;
    int u0 = blockIdx.x * 64, c0 = blockIdx.y * 64;
    int t = threadIdx.x;
    {
        int ul = t & 63, cl0 = t >> 6;
        const float* src = img + ((size_t)b * C3 + c0) * L + u0;
        #pragma unroll
        for (int r = 0; r < 16; ++r) {
            int cl = cl0 + r * 4;
            tile[cl][ul] = src[(size_t)cl * L + ul];
        }
    }
    __syncthreads();
    {
        int cl = t & 63, ul0 = t >> 6;
        __bf16* oh = dh + ((size_t)b * L + u0) * GK + c0 + cl;
        __bf16* ol = dl + ((size_t)b * L + u0) * GK + c0 + cl;
        #pragma unroll
        for (int r = 0; r < 16; ++r) {
            int ul = ul0 + r * 4;
            float v = tile[cl][ul];
            __bf16 h = (__bf16)v;
            float lo = v - (float)h;
            oh[(size_t)ul * GK] = h;
            ol[(size_t)ul * GK] = (__bf16)lo;
        }
    }
}

// ---------------- split-bf16 MFMA GEMM NT over K=256: G[u,v] ----------------
__global__ __launch_bounds__(256) void gemm_g(const __bf16* __restrict__ Khi,
                                              const __bf16* __restrict__ Klo,
                                              const __bf16* __restrict__ Qhi,
                                              const __bf16* __restrict__ Qlo,
                                              float* __restrict__ Gg) {
    __shared__ __align__(16) __bf16 Ah[64 * BK2];
    __shared__ __align__(16) __bf16 Al[64 * BK2];
    __shared__ __align__(16) __bf16 Bh[128 * BK2];
    __shared__ __align__(16) __bf16 Bl[128 * BK2];
    int t = threadIdx.x;
    int lane = t & 63;
    int wv = t >> 6;
    int b = blockIdx.z;
    size_t ioff = (size_t)b * L * GK;
    const __bf16* Ahg = Khi + ioff;   // rows u (refsr)
    const __bf16* Alg = Klo + ioff;
    const __bf16* Bhg = Qhi + ioff;   // rows v (lr)
    const __bf16* Blg = Qlo + ioff;
    int m0 = blockIdx.x * 128;
    int l0 = blockIdx.y * 64;
    int wl = wv >> 1, wm = wv & 1;    // wave tile: 32(u) x 64(v)
    int q = lane >> 4, r16 = lane & 15;

    f32x4 acc[2][4];
    #pragma unroll
    for (int i = 0; i < 2; i++)
        #pragma unroll
        for (int j = 0; j < 4; j++) acc[i][j] = (f32x4)(0.f);

    for (int k0 = 0; k0 < GK; k0 += BK2) {
        #pragma unroll
        for (int hh = 0; hh < 2; ++hh) {          // A: 512 chunks of 16B
            int c = t + hh * 256;
            int row = c >> 3, qo = c & 7;
            size_t ga = (size_t)(l0 + row) * GK + k0 + ((qo ^ (row & 7)) * 8);
            gload16(Ahg + ga, &Ah[c * 8]);
            gload16(Alg + ga, &Al[c * 8]);
        }
        #pragma unroll
        for (int hh = 0; hh < 4; ++hh) {          // B: 1024 chunks
            int c = t + hh * 256;
            int row = c >> 3, qo = c & 7;
            size_t gb = (size_t)(m0 + row) * GK + k0 + ((qo ^ (row & 7)) * 8);
            gload16(Bhg + gb, &Bh[c * 8]);
            gload16(Blg + gb, &Bl[c * 8]);
        }
        __syncthreads();

        #pragma unroll
        for (int h = 0; h < 2; ++h) {             // two k-32 halves of BK=64
            bf16x8 ah[2], al[2], bh[4], bl[4];
            #pragma unroll
            for (int i = 0; i < 2; ++i) {
                int row = wl * 32 + i * 16 + r16;
                int ch = (h * 4 + q) ^ (row & 7);
                ah[i] = *(const bf16x8*)&Ah[row * BK2 + ch * 8];
                al[i] = *(const bf16x8*)&Al[row * BK2 + ch * 8];
            }
            #pragma unroll
            for (int j = 0; j < 4; ++j) {
                int row = wm * 64 + j * 16 + r16;
                int ch = (h * 4 + q) ^ (row & 7);
                bh[j] = *(const bf16x8*)&Bh[row * BK2 + ch * 8];
                bl[j] = *(const bf16x8*)&Bl[row * BK2 + ch * 8];
            }
            #pragma unroll
            for (int i = 0; i < 2; ++i)
                #pragma unroll
                for (int j = 0; j < 4; ++j) {
                    acc[i][j] = __builtin_amdgcn_mfma_f32_16x16x32_bf16(ah[i], bh[j], acc[i][j], 0, 0, 0);
                    acc[i][j] = __builtin_amdgcn_mfma_f32_16x16x32_bf16(ah[i], bl[j], acc[i][j], 0, 0, 0);
                    acc[i][j] = __builtin_amdgcn_mfma_f32_16x16x32_bf16(al[i], bh[j], acc[i][j], 0, 0, 0);
                }
        }
        __syncthreads();
    }

    float* Cb = Gg + (size_t)b * L * L;
    #pragma unroll
    for (int i = 0; i < 2; ++i) {
        int rowb = l0 + wl * 32 + i * 16 + q * 4;
        #pragma unroll
        for (int j = 0; j < 4; ++j) {
            int col = m0 + wm * 64 + j * 16 + r16;
            #pragma unroll
            for (int r = 0; r < 4; ++r)
                Cb[(size_t)(rowb + r) * L + col] = acc[i][j][r];
        }
    }
}

// ---------------- R[l,m] = rnK[l]*rnQ[m]*sum_{9 diag shifts} G[l+s, m+s] ----------------
__global__ __launch_bounds__(576) void stencil_R(const float* __restrict__ G,
                                                 const float* __restrict__ rnK,
                                                 const float* __restrict__ rnQ,
                                                 float* __restrict__ R) {
    int blk = blockIdx.x;                 // 0..1151
    int xcd = blk & 7, idx = blk >> 3;    // 144 chunks per XCD
    int gc = xcd * 144 + idx;             // contiguous l-chunks per XCD
    int b = gc / 576;
    int lbase = (gc % 576) * 4;
    int m0 = threadIdx.x * 4;
    const float* Gb = G + (size_t)b * L * L;
    int mdiv0 = m0 / 48, mmod0 = m0 % 48; // 4 cols never straddle a 48-boundary
    const float* rq = rnQ + b * L + m0;
    float rqv0 = rq[0], rqv1 = rq[1], rqv2 = rq[2], rqv3 = rq[3];

    #pragma unroll
    for (int li = 0; li < 4; ++li) {
        int l = lbase + li;
        int ly = l / 48, lx = l % 48;
        float a0 = 0.f, a1 = 0.f, a2 = 0.f, a3 = 0.f;
        #pragma unroll
        for (int dy = -1; dy <= 1; ++dy) {
            if ((unsigned)(ly + dy) >= 48u) continue;
            if ((unsigned)(mdiv0 + dy) >= 48u) continue;    // uniform over the 4 cols
            #pragma unroll
            for (int dx = -1; dx <= 1; ++dx) {
                if ((unsigned)(lx + dx) >= 48u) continue;
                int s = dy * 48 + dx;
                f32x4u v = *(const f32x4u*)(Gb + (size_t)(l + s) * L + s + m0);
                bool e0 = (unsigned)(mmod0 + dx) < 48u;     // only j=0,dx=-1 can fail
                bool e3 = (unsigned)(mmod0 + 3 + dx) < 48u; // only j=3,dx=+1 can fail
                a0 += e0 ? v[0] : 0.f;
                a1 += v[1];
                a2 += v[2];
                a3 += e3 ? v[3] : 0.f;
            }
        }
        float rk = rnK[b * L + l];
        f32x4 o = { a0 * rk * rqv0, a1 * rk * rqv1, a2 * rk * rqv2, a3 * rk * rqv3 };
        *(f32x4*)(R + (size_t)b * L * L + (size_t)l * L + m0) = o;  // cached: re-read by argmax/top3
    }
}

// ---------------- segmented argmax over l (ties -> lowest l) ----------------
__global__ void argmax_part(const float* __restrict__ R, float* __restrict__ pv, int* __restrict__ pi) {
    int m = blockIdx.x * 256 + threadIdx.x;
    int seg = blockIdx.y, b = blockIdx.z;
    const float* Rb = R + (size_t)b * L * L;
    float bv = -3.4e38f; int bi = 0;
    int l0 = seg * SEG;
    #pragma unroll 4
    for (int j = 0; j < SEG; j++) {
        float v = Rb[(size_t)(l0 + j) * L + m];
        if (v > bv) { bv = v; bi = l0 + j; }
    }
    int o = (b * NSEG + seg) * L + m;
    pv[o] = bv; pi[o] = bi;
}

// ---------------- segmented top-3; fuses the argmax merge (hidx) in-block ----------------
__global__ void top3_part(const float* __restrict__ R, const float* __restrict__ apv,
                          const int* __restrict__ api,
                          float* __restrict__ pv, int* __restrict__ pr) {
    int m = blockIdx.x * 256 + threadIdx.x;
    int seg = blockIdx.y, b = blockIdx.z;
    const float* Rb = R + (size_t)b * L * L;
    __shared__ int hrow_s[SEG];
    if (threadIdx.x < SEG) {
        int l = seg * SEG + threadIdx.x;
        float bv = -3.4e38f; int bi = 0;
        #pragma unroll
        for (int s = 0; s < NSEG; s++) {
            int o = (b * NSEG + s) * L + l;
            float v = apv[o];
            if (v > bv) { bv = v; bi = api[o]; }
        }
        hrow_s[threadIdx.x] = bi;
    }
    __syncthreads();
    float v0 = -3.4e38f, v1 = -3.4e38f, v2 = -3.4e38f;
    int r0 = 0, r1 = 0, r2 = 0;
    #pragma unroll 4
    for (int j = 0; j < SEG; j++) {
        int row = hrow_s[j];
        float v = Rb[(size_t)row * L + m];
        if (v > v0)      { v2 = v1; r2 = r1; v1 = v0; r1 = r0; v0 = v; r0 = row; }
        else if (v > v1) { v2 = v1; r2 = r1; v1 = v;  r1 = row; }
        else if (v > v2) { v2 = v;  r2 = row; }
    }
    size_t o = ((size_t)(b * NSEG + seg) * 3) * L + m;
    pv[o] = v0; pv[o + L] = v1; pv[o + 2 * L] = v2;
    pr[o] = r0; pr[o + L] = r1; pr[o + 2 * L] = r2;
}

__global__ void top3_merge(const float* __restrict__ pv, const int* __restrict__ pr,
                           float* __restrict__ outS, int* __restrict__ effp) {
    int m = blockIdx.x * 256 + threadIdx.x;
    int b = blockIdx.y;
    float v0 = -3.4e38f, v1 = -3.4e38f, v2 = -3.4e38f;
    int r0 = 0, r1 = 0, r2 = 0;
    for (int s = 0; s < NSEG; s++) {
        size_t o = ((size_t)(b * NSEG + s) * 3) * L + m;
        #pragma unroll
        for (int j = 0; j < 3; j++) {
            float v = pv[o + (size_t)j * L];
            int r = pr[o + (size_t)j * L];
            if (v > v0)      { v2 = v1; r2 = r1; v1 = v0; r1 = r0; v0 = v; r0 = r; }
            else if (v > v1) { v2 = v1; r2 = r1; v1 = v;  r1 = r; }
            else if (v > v2) { v2 = v;  r2 = r; }
        }
    }
    outS[(0 * BATCH + b) * L + m] = v0;
    outS[(1 * BATCH + b) * L + m] = v1;
    outS[(2 * BATCH + b) * L + m] = v2;
    effp[(b * 3 + 0) * L + m] = ((r0 / 48) << 8) | (r0 % 48);
    effp[(b * 3 + 1) * L + m] = ((r1 / 48) << 8) | (r1 % 48);
    effp[(b * 3 + 2) * L + m] = ((r2 / 48) << 8) | (r2 % 48);
}

// ---------------- folds (all LDS-staged, all <= 46KB LDS) ----------------
// T1 row-split v2: block = one (plane, i, py); stage row-slice py patch-major
// (36.9KB). Thread loops over 4 SINGLE quads (qid = t + k*576) so each nts4 is
// 16B/lane CONTIGUOUS across the wave (fold_t1p's proven store pattern) -- v1's
// 4-adjacent-quad mapping made every store 16B at 64B lane-stride, 2.1x write
// amplification (WRITE_SIZE 121MB vs 57MB ideal).
__global__ __launch_bounds__(576) void fold_t1r(const float* __restrict__ ref, const int* __restrict__ effp,
                                                float* __restrict__ outT) {
    const int W = 192;
    __shared__ float sP[2304 * 4];         // 36.9 KB: row py of every 4x4 patch
    __shared__ int   sE[48 * 49];          // 9.2 KB ep table, stride 49
    int blk = blockIdx.x;                  // 1536 = 8 xcd * 192
    int xcd = blk & 7;
    int gc = xcd * 192 + (blk >> 3);       // contiguous chunks per XCD
    int py = gc & 3;
    int q = gc >> 2;                       // 0..383
    int i = q % 3, plane = q / 3;          // plane = b*64 + c
    int b = plane >> 6, c = plane & 63;
    int t = threadIdx.x;

    {   // stage row-slice: 4 coalesced f32x4 per thread (rows qy*4+py)
        const float* src = ref + (size_t)plane * (W * W);
        #pragma unroll
        for (int k = 0; k < 4; ++k) {
            int id = t + k * 576;          // 2304 chunks: qy*48 + qx
            int qy = id / 48, qx = id % 48;
            f32x4 v = *(const f32x4*)(src + (qy * 4 + py) * W + qx * 4);
            *(f32x4*)&sP[id * 4] = v;
        }
        const int* e = effp + (b * 3 + i) * L;
        i32x4 ev = *(const i32x4*)(e + t * 4);
        #pragma unroll
        for (int k = 0; k < 4; ++k) {
            int id = t * 4 + k;
            sE[(id / 48) * 49 + (id % 48)] = ev[k];
        }
    }
    __syncthreads();

    const float kk = 1.0f / 9.0f;
    float* dstp = outT + (((size_t)i * BATCH + b) * C1 + c) * (size_t)(W * W);
    #pragma unroll
    for (int k = 0; k < 4; ++k) {
        int qid = t + k * 576;             // one quad per iteration
        int qy = qid / 48, qx = qid % 48;
        f32x4 acc = (f32x4)(0.f);
        #pragma unroll
        for (int dh = -1; dh <= 1; ++dh) {
            int ho = qy + dh;
            if ((unsigned)ho >= 48u) continue;
            #pragma unroll
            for (int dw = -1; dw <= 1; ++dw) {
                int wo = qx + dw;
                if ((unsigned)wo >= 48u) continue;
                int ep = sE[ho * 49 + wo];
                int yq = (ep >> 8) - dh, xq = (ep & 255) - dw;
                if ((unsigned)yq >= 48u || (unsigned)xq >= 48u) continue;
                acc += *(const f32x4*)&sP[(yq * 48 + xq) * 4];
            }
        }
        nts4(dstp + (qy * 4 + py) * W + qx * 4,
             acc[0] * kk, acc[1] * kk, acc[2] * kk, acc[3] * kk);
    }
}

// T2: LDS-staged (proven R5).
__global__ __launch_bounds__(576) void fold_t2_lds(const float* __restrict__ ref, const int* __restrict__ effp,
                                                   float* __restrict__ outT) {
    const int W = 96;
    __shared__ float sP[2304 * 4];         // 36.9 KB patch-major plane
    __shared__ int   sE[48 * 49];          // 9.4 KB ep table, stride 49
    int blk = blockIdx.x;                  // 768 = 8 xcd * 96
    int xcd = blk & 7;
    int gc = xcd * 96 + (blk >> 3);        // contiguous chunks per XCD
    int plane = gc / 3, i = gc % 3;        // plane = b*128 + c
    int b = plane >> 7, c = plane & 127;
    int t = threadIdx.x;

    {   // stage plane: 4 coalesced f32x4 per thread -> patch-major ds_write_b64 pairs
        const float* src = ref + (size_t)plane * (W * W);
        #pragma unroll
        for (int k = 0; k < 4; ++k) {
            int id = t + k * 576;          // f32x4 chunk id over the plane
            int row = id / 24, x4 = id % 24;
            f32x4 v = *(const f32x4*)(src + row * W + x4 * 4);
            int qy = row >> 1, py = row & 1;
            int base0 = (qy * 48 + 2 * x4) * 4 + py * 2;
            f32x2 lo = { v[0], v[1] }, hi = { v[2], v[3] };
            *(f32x2*)&sP[base0] = lo;
            *(f32x2*)&sP[base0 + 4] = hi;
        }
        const int* e = effp + (b * 3 + i) * L;
        i32x4 ev = *(const i32x4*)(e + t * 4);
        #pragma unroll
        for (int k = 0; k < 4; ++k) {
            int id = t * 4 + k;
            sE[(id / 48) * 49 + (id % 48)] = ev[k];
        }
    }
    __syncthreads();

    int y = t / 12, x0q = (t % 12) * 4;    // 4 x-adjacent quads per thread
    f32x4 acc[4];
    #pragma unroll
    for (int xi = 0; xi < 4; ++xi) acc[xi] = (f32x4)(0.f);
    #pragma unroll
    for (int dh = -1; dh <= 1; ++dh) {
        int ho = y + dh;
        if ((unsigned)ho >= 48u) continue;
        int ep6[6];
        #pragma unroll
        for (int j = 0; j < 6; ++j) {
            int wo = x0q - 1 + j;
            ep6[j] = ((unsigned)wo < 48u) ? sE[ho * 49 + wo] : -1;
        }
        #pragma unroll
        for (int xi = 0; xi < 4; ++xi) {
            #pragma unroll
            for (int dw = -1; dw <= 1; ++dw) {
                int ep = ep6[xi + dw + 1];
                if (ep < 0) continue;
                int yq = (ep >> 8) - dh, xq = (ep & 255) - dw;
                if ((unsigned)yq >= 48u || (unsigned)xq >= 48u) continue;
                acc[xi] += *(const f32x4*)&sP[(yq * 48 + xq) * 4];
            }
        }
    }
    const float k = 1.0f / 9.0f;
    float* dst = outT + (((size_t)i * BATCH + b) * C2 + c) * (size_t)(W * W) + (2 * y) * W + x0q * 2;
    nts4(dst,         acc[0][0] * k, acc[0][1] * k, acc[1][0] * k, acc[1][1] * k);
    nts4(dst + 4,     acc[2][0] * k, acc[2][1] * k, acc[3][0] * k, acc[3][1] * k);
    nts4(dst + W,     acc[0][2] * k, acc[0][3] * k, acc[1][2] * k, acc[1][3] * k);
    nts4(dst + W + 4, acc[2][2] * k, acc[2][3] * k, acc[3][2] * k, acc[3][3] * k);
}

// T3: LDS-staged gather (proven R4).
__global__ __launch_bounds__(576) void fold_t3_lds(const float* __restrict__ ref, const int* __restrict__ effp,
                                                   float* __restrict__ outT) {
    const int W = 48;
    __shared__ float sP[2304];
    __shared__ int   sE[48 * 49];          // stride 49: rotates banks per row
    int blk = blockIdx.x;                  // 1536 = 8 xcd * 192
    int xcd = blk & 7;
    int gc = xcd * 192 + (blk >> 3);       // contiguous plane-chunks per XCD
    int plane = gc / 3, i = gc % 3;        // plane = b*256 + c
    int b = plane >> 8, c = plane & 255;
    int t = threadIdx.x;

    {   // stage plane (one float4/thread) + ep table (one int4/thread, re-padded)
        const float* src = ref + (size_t)plane * (W * W);
        *(f32x4*)&sP[t * 4] = *(const f32x4*)(src + t * 4);
        const int* e = effp + (b * 3 + i) * L;
        i32x4 ev = *(const i32x4*)(e + t * 4);
        #pragma unroll
        for (int k = 0; k < 4; ++k) {
            int id = t * 4 + k;
            sE[(id / 48) * 49 + (id % 48)] = ev[k];
        }
    }
    __syncthreads();

    int y = t / 12, x0 = (t % 12) * 4;     // 576 threads cover 48x12 quads of 4 px
    float s0 = 0.f, s1 = 0.f, s2 = 0.f, s3 = 0.f;
    #pragma unroll
    for (int dh = -1; dh <= 1; ++dh) {
        int ho = y + dh;
        if ((unsigned)ho >= 48u) continue;
        int ep6[6];
        #pragma unroll
        for (int j = 0; j < 6; ++j) {
            int wo = x0 - 1 + j;
            ep6[j] = ((unsigned)wo < 48u) ? sE[ho * 49 + wo] : -1;
        }
        #pragma unroll
        for (int xi = 0; xi < 4; ++xi) {
            float acc = 0.f;
            #pragma unroll
            for (int dw = -1; dw <= 1; ++dw) {
                int ep = ep6[xi + dw + 1];
                if (ep < 0) continue;
                int yy = (ep >> 8) - dh, xx = (ep & 255) - dw;
                if ((unsigned)yy >= 48u || (unsigned)xx >= 48u) continue;
                acc += sP[yy * W + xx];
            }
            if (xi == 0) s0 += acc; else if (xi == 1) s1 += acc;
            else if (xi == 2) s2 += acc; else s3 += acc;
        }
    }
    const float k = 1.0f / 9.0f;
    nts4(outT + (((size_t)i * BATCH + b) * C3 + c) * (size_t)(W * W) + y * W + x0,
         s0 * k, s1 * k, s2 * k, s3 * k);
}

extern "C" void kernel_launch(void* const* d_in, const int* in_sizes, int n_in,
                              void* d_out, int out_size, void* d_ws, size_t ws_size,
                              hipStream_t stream) {
    const float* lr    = (const float*)d_in[0];
    const float* refsr = (const float*)d_in[1];
    const float* ref1  = (const float*)d_in[2];
    const float* ref2  = (const float*)d_in[3];
    const float* ref3  = (const float*)d_in[4];
    float* out = (float*)d_out;

    float*  R   = (float*)d_ws;                              // B*L*L fp32
    float*  G   = R + (size_t)BATCH * L * L;                 // B*L*L fp32
    __bf16* Khi = (__bf16*)(G + (size_t)BATCH * L * L);      // B*L*GK bf16 each
    __bf16* Klo = Khi + (size_t)BATCH * L * GK;
    __bf16* Qhi = Klo + (size_t)BATCH * L * GK;
    __bf16* Qlo = Qhi + (size_t)BATCH * L * GK;
    float* ssQ4 = (float*)(Qlo + (size_t)BATCH * L * GK);    // 4 * B*L
    float* ssK4 = ssQ4 + 4 * BATCH * L;
    float* rnQ = ssK4 + 4 * BATCH * L;
    float* rnK = rnQ + BATCH * L;
    float* apv = rnK + BATCH * L;
    float* pv  = apv + BATCH * NSEG * L;
    int*   api = (int*)(pv + (size_t)BATCH * NSEG * 3 * L);
    int*   pr  = api + BATCH * NSEG * L;
    int*   effp = pr + (size_t)BATCH * NSEG * 3 * L;

    ssq_kernel<<<dim3(18, 8), 256, 0, stream>>>(lr, refsr, ssQ4, ssK4);
    norm_kernel<<<dim3(18, 2), 256, 0, stream>>>(ssQ4, ssK4, rnQ, rnK);
    split_t<<<dim3(36, 4, BATCH * 2), 256, 0, stream>>>(lr, refsr, Qhi, Qlo, Khi, Klo);

    gemm_g<<<dim3(18, 36, BATCH), 256, 0, stream>>>(Khi, Klo, Qhi, Qlo, G);
    stencil_R<<<1152, 576, 0, stream>>>(G, rnK, rnQ, R);

    argmax_part<<<dim3(9, NSEG, BATCH), 256, 0, stream>>>(R, apv, api);
    top3_part<<<dim3(9, NSEG, BATCH), 256, 0, stream>>>(R, apv, api, pv, pr);
    top3_merge<<<dim3(9, BATCH), 256, 0, stream>>>(pv, pr, out, effp);

    fold_t3_lds<<<1536, 576, 0, stream>>>(ref3, effp, out + OFF_T3);
    fold_t2_lds<<<768,  576, 0, stream>>>(ref2, effp, out + OFF_T2);
    fold_t1r<<<1536, 576, 0, stream>>>(ref1, effp, out + OFF_T1);
}

// Round 10
// 296.745 us; speedup vs baseline: 1.3898x; 1.1838x over previous
//
#include <hip/hip_runtime.h>
#include <math.h>

// Problem constants
#define BATCH 2
#define C3 256
#define C2 128
#define C1 64
#define HH 48
#define WW 48
#define L 2304          // 48*48 unfold positions
#define GK 256          // channel dim for G-GEMM
#define BK2 64          // K-tile (bf16) for G-GEMM
#define NSEG 32
#define SEG 72          // 2304/32

// Output flat offsets (float elements)
#define OFF_T3 13824
#define OFF_T2 3552768
#define OFF_T1 10630656

typedef __bf16 bf16x8 __attribute__((ext_vector_type(8)));
typedef float  f32x4  __attribute__((ext_vector_type(4)));
typedef float  f32x2  __attribute__((ext_vector_type(2)));
typedef int    i32x4  __attribute__((ext_vector_type(4)));
// dword-aligned (not 16B) float4 for shifted stencil loads
typedef float  f32x4u __attribute__((ext_vector_type(4), aligned(4)));

__device__ __forceinline__ void gload16(const void* g, void* l) {
    __builtin_amdgcn_global_load_lds(
        (const __attribute__((address_space(1))) void*)g,
        (__attribute__((address_space(3))) void*)l, 16, 0, 0);
}

__device__ __forceinline__ void nts4(float* p, float a, float b, float c, float d) {
    f32x4 v = {a, b, c, d};
    __builtin_nontemporal_store(v, (f32x4*)p);
}
__device__ __forceinline__ void nts2(float* p, float a, float b) {
    f32x2 v = {a, b};
    __builtin_nontemporal_store(v, (f32x2*)p);
}

// ---------------- per-pixel channel sum of squares, 4-way channel split ----------------
__global__ void ssq_kernel(const float* __restrict__ lr, const float* __restrict__ refsr,
                           float* __restrict__ ssQ4, float* __restrict__ ssK4) {
    int idx = blockIdx.x * 256 + threadIdx.x;
    if (idx >= BATCH * L) return;
    int img_i = blockIdx.y & 1, seg = blockIdx.y >> 1;
    const float* img = img_i ? refsr : lr;
    float* ss = (img_i ? ssK4 : ssQ4) + seg * (BATCH * L);
    int b = idx / L, yx = idx % L;
    const float* p = img + ((size_t)b * C3 + seg * 64) * L + yx;
    float s = 0.f;
    #pragma unroll 4
    for (int c = 0; c < 64; ++c) { float v = p[(size_t)c * L]; s += v * v; }
    ss[idx] = s;
}

// ---------------- 3x3 window sum over 4 partials -> 1/max(sqrt, eps) (both) ----------------
__global__ void norm_kernel(const float* __restrict__ ssQ4, const float* __restrict__ ssK4,
                            float* __restrict__ rnQ, float* __restrict__ rnK) {
    int idx = blockIdx.x * 256 + threadIdx.x;
    if (idx >= BATCH * L) return;
    const float* ss = blockIdx.y ? ssK4 : ssQ4;
    float* rn = blockIdx.y ? rnK : rnQ;
    int b = idx / L, l = idx % L;
    int ly = l / WW, lx = l % WW;
    const float* s = ss + b * L;
    float acc = 0.f;
    #pragma unroll
    for (int dy = -1; dy <= 1; ++dy) {
        int yy = ly + dy;
        if ((unsigned)yy >= (unsigned)HH) continue;
        #pragma unroll
        for (int dx = -1; dx <= 1; ++dx) {
            int xx = lx + dx;
            if ((unsigned)xx >= (unsigned)WW) continue;
            int o = yy * WW + xx;
            acc += s[o] + s[BATCH * L + o] + s[2 * BATCH * L + o] + s[3 * BATCH * L + o];
        }
    }
    float n = sqrtf(acc);
    n = fmaxf(n, 1e-12f);
    rn[idx] = 1.0f / n;
}

// ---------------- transpose [C][pix] -> [pix][C] + bf16 hi/lo split (both images) ----
__global__ __launch_bounds__(256) void split_t(const float* __restrict__ lr,
                                               const float* __restrict__ refsr,
                                               __bf16* __restrict__ Qhi, __bf16* __restrict__ Qlo,
                                               __bf16* __restrict__ Khi, __bf16* __restrict__ Klo) {
    __shared__ float tile[64][65];
    int bz = blockIdx.z;
    int b = bz >> 1;
    const float* img = (bz & 1) ? refsr : lr;
    __bf16* dh = (bz & 1) ? Khi : Qhi;
    __bf16* dl = (bz & 1) ? Klo : Qlo;
    int u0 = blockIdx.x * 64, c0 = blockIdx.y * 64;
    int t = threadIdx.x;
    {
        int ul = t & 63, cl0 = t >> 6;
        const float* src = img + ((size_t)b * C3 + c0) * L + u0;
        #pragma unroll
        for (int r = 0; r < 16; ++r) {
            int cl = cl0 + r * 4;
            tile[cl][ul] = src[(size_t)cl * L + ul];
        }
    }
    __syncthreads();
    {
        int cl = t & 63, ul0 = t >> 6;
        __bf16* oh = dh + ((size_t)b * L + u0) * GK + c0 + cl;
        __bf16* ol = dl + ((size_t)b * L + u0) * GK + c0 + cl;
        #pragma unroll
        for (int r = 0; r < 16; ++r) {
            int ul = ul0 + r * 4;
            float v = tile[cl][ul];
            __bf16 h = (__bf16)v;
            float lo = v - (float)h;
            oh[(size_t)ul * GK] = h;
            ol[(size_t)ul * GK] = (__bf16)lo;
        }
    }
}

// ---------------- split-bf16 MFMA GEMM NT over K=256: G[u,v] ----------------
__global__ __launch_bounds__(256) void gemm_g(const __bf16* __restrict__ Khi,
                                              const __bf16* __restrict__ Klo,
                                              const __bf16* __restrict__ Qhi,
                                              const __bf16* __restrict__ Qlo,
                                              float* __restrict__ Gg) {
    __shared__ __align__(16) __bf16 Ah[64 * BK2];
    __shared__ __align__(16) __bf16 Al[64 * BK2];
    __shared__ __align__(16) __bf16 Bh[128 * BK2];
    __shared__ __align__(16) __bf16 Bl[128 * BK2];
    int t = threadIdx.x;
    int lane = t & 63;
    int wv = t >> 6;
    int b = blockIdx.z;
    size_t ioff = (size_t)b * L * GK;
    const __bf16* Ahg = Khi + ioff;   // rows u (refsr)
    const __bf16* Alg = Klo + ioff;
    const __bf16* Bhg = Qhi + ioff;   // rows v (lr)
    const __bf16* Blg = Qlo + ioff;
    int m0 = blockIdx.x * 128;
    int l0 = blockIdx.y * 64;
    int wl = wv >> 1, wm = wv & 1;    // wave tile: 32(u) x 64(v)
    int q = lane >> 4, r16 = lane & 15;

    f32x4 acc[2][4];
    #pragma unroll
    for (int i = 0; i < 2; i++)
        #pragma unroll
        for (int j = 0; j < 4; j++) acc[i][j] = (f32x4)(0.f);

    for (int k0 = 0; k0 < GK; k0 += BK2) {
        #pragma unroll
        for (int hh = 0; hh < 2; ++hh) {          // A: 512 chunks of 16B
            int c = t + hh * 256;
            int row = c >> 3, qo = c & 7;
            size_t ga = (size_t)(l0 + row) * GK + k0 + ((qo ^ (row & 7)) * 8);
            gload16(Ahg + ga, &Ah[c * 8]);
            gload16(Alg + ga, &Al[c * 8]);
        }
        #pragma unroll
        for (int hh = 0; hh < 4; ++hh) {          // B: 1024 chunks
            int c = t + hh * 256;
            int row = c >> 3, qo = c & 7;
            size_t gb = (size_t)(m0 + row) * GK + k0 + ((qo ^ (row & 7)) * 8);
            gload16(Bhg + gb, &Bh[c * 8]);
            gload16(Blg + gb, &Bl[c * 8]);
        }
        __syncthreads();

        #pragma unroll
        for (int h = 0; h < 2; ++h) {             // two k-32 halves of BK=64
            bf16x8 ah[2], al[2], bh[4], bl[4];
            #pragma unroll
            for (int i = 0; i < 2; ++i) {
                int row = wl * 32 + i * 16 + r16;
                int ch = (h * 4 + q) ^ (row & 7);
                ah[i] = *(const bf16x8*)&Ah[row * BK2 + ch * 8];
                al[i] = *(const bf16x8*)&Al[row * BK2 + ch * 8];
            }
            #pragma unroll
            for (int j = 0; j < 4; ++j) {
                int row = wm * 64 + j * 16 + r16;
                int ch = (h * 4 + q) ^ (row & 7);
                bh[j] = *(const bf16x8*)&Bh[row * BK2 + ch * 8];
                bl[j] = *(const bf16x8*)&Bl[row * BK2 + ch * 8];
            }
            #pragma unroll
            for (int i = 0; i < 2; ++i)
                #pragma unroll
                for (int j = 0; j < 4; ++j) {
                    acc[i][j] = __builtin_amdgcn_mfma_f32_16x16x32_bf16(ah[i], bh[j], acc[i][j], 0, 0, 0);
                    acc[i][j] = __builtin_amdgcn_mfma_f32_16x16x32_bf16(ah[i], bl[j], acc[i][j], 0, 0, 0);
                    acc[i][j] = __builtin_amdgcn_mfma_f32_16x16x32_bf16(al[i], bh[j], acc[i][j], 0, 0, 0);
                }
        }
        __syncthreads();
    }

    float* Cb = Gg + (size_t)b * L * L;
    #pragma unroll
    for (int i = 0; i < 2; ++i) {
        int rowb = l0 + wl * 32 + i * 16 + q * 4;
        #pragma unroll
        for (int j = 0; j < 4; ++j) {
            int col = m0 + wm * 64 + j * 16 + r16;
            #pragma unroll
            for (int r = 0; r < 4; ++r)
                Cb[(size_t)(rowb + r) * L + col] = acc[i][j][r];
        }
    }
}

// ---------------- R[l,m] = rnK[l]*rnQ[m]*sum_{9 diag shifts} G[l+s, m+s] ----------------
__global__ __launch_bounds__(576) void stencil_R(const float* __restrict__ G,
                                                 const float* __restrict__ rnK,
                                                 const float* __restrict__ rnQ,
                                                 float* __restrict__ R) {
    int blk = blockIdx.x;                 // 0..1151
    int xcd = blk & 7, idx = blk >> 3;    // 144 chunks per XCD
    int gc = xcd * 144 + idx;             // contiguous l-chunks per XCD
    int b = gc / 576;
    int lbase = (gc % 576) * 4;
    int m0 = threadIdx.x * 4;
    const float* Gb = G + (size_t)b * L * L;
    int mdiv0 = m0 / 48, mmod0 = m0 % 48; // 4 cols never straddle a 48-boundary
    const float* rq = rnQ + b * L + m0;
    float rqv0 = rq[0], rqv1 = rq[1], rqv2 = rq[2], rqv3 = rq[3];

    #pragma unroll
    for (int li = 0; li < 4; ++li) {
        int l = lbase + li;
        int ly = l / 48, lx = l % 48;
        float a0 = 0.f, a1 = 0.f, a2 = 0.f, a3 = 0.f;
        #pragma unroll
        for (int dy = -1; dy <= 1; ++dy) {
            if ((unsigned)(ly + dy) >= 48u) continue;
            if ((unsigned)(mdiv0 + dy) >= 48u) continue;    // uniform over the 4 cols
            #pragma unroll
            for (int dx = -1; dx <= 1; ++dx) {
                if ((unsigned)(lx + dx) >= 48u) continue;
                int s = dy * 48 + dx;
                f32x4u v = *(const f32x4u*)(Gb + (size_t)(l + s) * L + s + m0);
                bool e0 = (unsigned)(mmod0 + dx) < 48u;     // only j=0,dx=-1 can fail
                bool e3 = (unsigned)(mmod0 + 3 + dx) < 48u; // only j=3,dx=+1 can fail
                a0 += e0 ? v[0] : 0.f;
                a1 += v[1];
                a2 += v[2];
                a3 += e3 ? v[3] : 0.f;
            }
        }
        float rk = rnK[b * L + l];
        f32x4 o = { a0 * rk * rqv0, a1 * rk * rqv1, a2 * rk * rqv2, a3 * rk * rqv3 };
        *(f32x4*)(R + (size_t)b * L * L + (size_t)l * L + m0) = o;  // cached: re-read by argmax/top3
    }
}

// ---------------- segmented argmax over l (ties -> lowest l), batch-8 prefetch ----------------
__global__ void argmax_part(const float* __restrict__ R, float* __restrict__ pv, int* __restrict__ pi) {
    int m = blockIdx.x * 256 + threadIdx.x;
    int seg = blockIdx.y, b = blockIdx.z;
    const float* Rb = R + (size_t)b * L * L + m;
    float bv = -3.4e38f; int bi = 0;
    int l0 = seg * SEG;
    for (int j0 = 0; j0 < SEG; j0 += 8) {
        float vv[8];
        #pragma unroll
        for (int j = 0; j < 8; ++j) vv[j] = Rb[(size_t)(l0 + j0 + j) * L];
        #pragma unroll
        for (int j = 0; j < 8; ++j)
            if (vv[j] > bv) { bv = vv[j]; bi = l0 + j0 + j; }
    }
    int o = (b * NSEG + seg) * L + m;
    pv[o] = bv; pi[o] = bi;
}

// ---------------- argmax merge over 32 partials, batch-8 prefetch ----------------
__global__ void argmax_merge(const float* __restrict__ pv, const int* __restrict__ pi,
                             int* __restrict__ hidx) {
    int m = blockIdx.x * 256 + threadIdx.x;
    int b = blockIdx.y;
    float bv = -3.4e38f; int bi = 0;
    for (int s0 = 0; s0 < NSEG; s0 += 8) {
        float vv[8]; int rr[8];
        #pragma unroll
        for (int s = 0; s < 8; ++s) {
            int o = (b * NSEG + s0 + s) * L + m;
            vv[s] = pv[o]; rr[s] = pi[o];
        }
        #pragma unroll
        for (int s = 0; s < 8; ++s)
            if (vv[s] > bv) { bv = vv[s]; bi = rr[s]; }
    }
    hidx[b * L + m] = bi;
}

// ---------------- segmented top-3 of s_l = R[hidx[l], m], batch-8 prefetch ----------------
__global__ void top3_part(const float* __restrict__ R, const int* __restrict__ hidx,
                          float* __restrict__ pv, int* __restrict__ pr) {
    int m = blockIdx.x * 256 + threadIdx.x;
    int seg = blockIdx.y, b = blockIdx.z;
    const float* Rb = R + (size_t)b * L * L + m;
    __shared__ int hrow_s[SEG];
    if (threadIdx.x < SEG) hrow_s[threadIdx.x] = hidx[b * L + seg * SEG + threadIdx.x];
    __syncthreads();
    float v0 = -3.4e38f, v1 = -3.4e38f, v2 = -3.4e38f;
    int r0 = 0, r1 = 0, r2 = 0;
    for (int j0 = 0; j0 < SEG; j0 += 8) {
        float vv[8]; int rr[8];
        #pragma unroll
        for (int j = 0; j < 8; ++j) {
            int row = hrow_s[j0 + j];
            rr[j] = row;
            vv[j] = Rb[(size_t)row * L];
        }
        #pragma unroll
        for (int j = 0; j < 8; ++j) {
            float v = vv[j]; int r = rr[j];
            if (v > v0)      { v2 = v1; r2 = r1; v1 = v0; r1 = r0; v0 = v; r0 = r; }
            else if (v > v1) { v2 = v1; r2 = r1; v1 = v;  r1 = r; }
            else if (v > v2) { v2 = v;  r2 = r; }
        }
    }
    size_t o = ((size_t)(b * NSEG + seg) * 3) * L + m;
    pv[o] = v0; pv[o + L] = v1; pv[o + 2 * L] = v2;
    pr[o] = r0; pr[o + L] = r1; pr[o + 2 * L] = r2;
}

__global__ void top3_merge(const float* __restrict__ pv, const int* __restrict__ pr,
                           float* __restrict__ outS, int* __restrict__ effp) {
    int m = blockIdx.x * 256 + threadIdx.x;
    int b = blockIdx.y;
    float v0 = -3.4e38f, v1 = -3.4e38f, v2 = -3.4e38f;
    int r0 = 0, r1 = 0, r2 = 0;
    for (int s0 = 0; s0 < NSEG; s0 += 4) {        // batch 4 segments = 12 candidates
        float vv[12]; int rr[12];
        #pragma unroll
        for (int s = 0; s < 4; ++s)
            #pragma unroll
            for (int j = 0; j < 3; ++j) {
                size_t o = ((size_t)(b * NSEG + s0 + s) * 3 + j) * L + m;
                vv[s * 3 + j] = pv[o]; rr[s * 3 + j] = pr[o];
            }
        #pragma unroll
        for (int k = 0; k < 12; ++k) {
            float v = vv[k]; int r = rr[k];
            if (v > v0)      { v2 = v1; r2 = r1; v1 = v0; r1 = r0; v0 = v; r0 = r; }
            else if (v > v1) { v2 = v1; r2 = r1; v1 = v;  r1 = r; }
            else if (v > v2) { v2 = v;  r2 = r; }
        }
    }
    outS[(0 * BATCH + b) * L + m] = v0;
    outS[(1 * BATCH + b) * L + m] = v1;
    outS[(2 * BATCH + b) * L + m] = v2;
    effp[(b * 3 + 0) * L + m] = ((r0 / 48) << 8) | (r0 % 48);
    effp[(b * 3 + 1) * L + m] = ((r1 / 48) << 8) | (r1 % 48);
    effp[(b * 3 + 2) * L + m] = ((r2 / 48) << 8) | (r2 % 48);
}

// ---------------- folds (all LDS-staged, all <= 46KB LDS) ----------------
// T1 row-split v2 (proven R9): block = one (plane, i, py); per-quad thread loop
// so every nts4 is 16B/lane contiguous across the wave.
__global__ __launch_bounds__(576) void fold_t1r(const float* __restrict__ ref, const int* __restrict__ effp,
                                                float* __restrict__ outT) {
    const int W = 192;
    __shared__ float sP[2304 * 4];         // 36.9 KB: row py of every 4x4 patch
    __shared__ int   sE[48 * 49];          // 9.2 KB ep table, stride 49
    int blk = blockIdx.x;                  // 1536 = 8 xcd * 192
    int xcd = blk & 7;
    int gc = xcd * 192 + (blk >> 3);       // contiguous chunks per XCD
    int py = gc & 3;
    int q = gc >> 2;                       // 0..383
    int i = q % 3, plane = q / 3;          // plane = b*64 + c
    int b = plane >> 6, c = plane & 63;
    int t = threadIdx.x;

    {   // stage row-slice: 4 coalesced f32x4 per thread (rows qy*4+py)
        const float* src = ref + (size_t)plane * (W * W);
        #pragma unroll
        for (int k = 0; k < 4; ++k) {
            int id = t + k * 576;          // 2304 chunks: qy*48 + qx
            int qy = id / 48, qx = id % 48;
            f32x4 v = *(const f32x4*)(src + (qy * 4 + py) * W + qx * 4);
            *(f32x4*)&sP[id * 4] = v;
        }
        const int* e = effp + (b * 3 + i) * L;
        i32x4 ev = *(const i32x4*)(e + t * 4);
        #pragma unroll
        for (int k = 0; k < 4; ++k) {
            int id = t * 4 + k;
            sE[(id / 48) * 49 + (id % 48)] = ev[k];
        }
    }
    __syncthreads();

    const float kk = 1.0f / 9.0f;
    float* dstp = outT + (((size_t)i * BATCH + b) * C1 + c) * (size_t)(W * W);
    #pragma unroll
    for (int k = 0; k < 4; ++k) {
        int qid = t + k * 576;             // one quad per iteration
        int qy = qid / 48, qx = qid % 48;
        f32x4 acc = (f32x4)(0.f);
        #pragma unroll
        for (int dh = -1; dh <= 1; ++dh) {
            int ho = qy + dh;
            if ((unsigned)ho >= 48u) continue;
            #pragma unroll
            for (int dw = -1; dw <= 1; ++dw) {
                int wo = qx + dw;
                if ((unsigned)wo >= 48u) continue;
                int ep = sE[ho * 49 + wo];
                int yq = (ep >> 8) - dh, xq = (ep & 255) - dw;
                if ((unsigned)yq >= 48u || (unsigned)xq >= 48u) continue;
                acc += *(const f32x4*)&sP[(yq * 48 + xq) * 4];
            }
        }
        nts4(dstp + (qy * 4 + py) * W + qx * 4,
             acc[0] * kk, acc[1] * kk, acc[2] * kk, acc[3] * kk);
    }
}

// T2: LDS-staged (proven R5).
__global__ __launch_bounds__(576) void fold_t2_lds(const float* __restrict__ ref, const int* __restrict__ effp,
                                                   float* __restrict__ outT) {
    const int W = 96;
    __shared__ float sP[2304 * 4];         // 36.9 KB patch-major plane
    __shared__ int   sE[48 * 49];          // 9.4 KB ep table, stride 49
    int blk = blockIdx.x;                  // 768 = 8 xcd * 96
    int xcd = blk & 7;
    int gc = xcd * 96 + (blk >> 3);        // contiguous chunks per XCD
    int plane = gc / 3, i = gc % 3;        // plane = b*128 + c
    int b = plane >> 7, c = plane & 127;
    int t = threadIdx.x;

    {   // stage plane: 4 coalesced f32x4 per thread -> patch-major ds_write_b64 pairs
        const float* src = ref + (size_t)plane * (W * W);
        #pragma unroll
        for (int k = 0; k < 4; ++k) {
            int id = t + k * 576;          // f32x4 chunk id over the plane
            int row = id / 24, x4 = id % 24;
            f32x4 v = *(const f32x4*)(src + row * W + x4 * 4);
            int qy = row >> 1, py = row & 1;
            int base0 = (qy * 48 + 2 * x4) * 4 + py * 2;
            f32x2 lo = { v[0], v[1] }, hi = { v[2], v[3] };
            *(f32x2*)&sP[base0] = lo;
            *(f32x2*)&sP[base0 + 4] = hi;
        }
        const int* e = effp + (b * 3 + i) * L;
        i32x4 ev = *(const i32x4*)(e + t * 4);
        #pragma unroll
        for (int k = 0; k < 4; ++k) {
            int id = t * 4 + k;
            sE[(id / 48) * 49 + (id % 48)] = ev[k];
        }
    }
    __syncthreads();

    int y = t / 12, x0q = (t % 12) * 4;    // 4 x-adjacent quads per thread
    f32x4 acc[4];
    #pragma unroll
    for (int xi = 0; xi < 4; ++xi) acc[xi] = (f32x4)(0.f);
    #pragma unroll
    for (int dh = -1; dh <= 1; ++dh) {
        int ho = y + dh;
        if ((unsigned)ho >= 48u) continue;
        int ep6[6];
        #pragma unroll
        for (int j = 0; j < 6; ++j) {
            int wo = x0q - 1 + j;
            ep6[j] = ((unsigned)wo < 48u) ? sE[ho * 49 + wo] : -1;
        }
        #pragma unroll
        for (int xi = 0; xi < 4; ++xi) {
            #pragma unroll
            for (int dw = -1; dw <= 1; ++dw) {
                int ep = ep6[xi + dw + 1];
                if (ep < 0) continue;
                int yq = (ep >> 8) - dh, xq = (ep & 255) - dw;
                if ((unsigned)yq >= 48u || (unsigned)xq >= 48u) continue;
                acc[xi] += *(const f32x4*)&sP[(yq * 48 + xq) * 4];
            }
        }
    }
    const float k = 1.0f / 9.0f;
    float* dst = outT + (((size_t)i * BATCH + b) * C2 + c) * (size_t)(W * W) + (2 * y) * W + x0q * 2;
    nts4(dst,         acc[0][0] * k, acc[0][1] * k, acc[1][0] * k, acc[1][1] * k);
    nts4(dst + 4,     acc[2][0] * k, acc[2][1] * k, acc[3][0] * k, acc[3][1] * k);
    nts4(dst + W,     acc[0][2] * k, acc[0][3] * k, acc[1][2] * k, acc[1][3] * k);
    nts4(dst + W + 4, acc[2][2] * k, acc[2][3] * k, acc[3][2] * k, acc[3][3] * k);
}

// T3: LDS-staged gather (proven R4).
__global__ __launch_bounds__(576) void fold_t3_lds(const float* __restrict__ ref, const int* __restrict__ effp,
                                                   float* __restrict__ outT) {
    const int W = 48;
    __shared__ float sP[2304];
    __shared__ int   sE[48 * 49];          // stride 49: rotates banks per row
    int blk = blockIdx.x;                  // 1536 = 8 xcd * 192
    int xcd = blk & 7;
    int gc = xcd * 192 + (blk >> 3);       // contiguous plane-chunks per XCD
    int plane = gc / 3, i = gc % 3;        // plane = b*256 + c
    int b = plane >> 8, c = plane & 255;
    int t = threadIdx.x;

    {   // stage plane (one float4/thread) + ep table (one int4/thread, re-padded)
        const float* src = ref + (size_t)plane * (W * W);
        *(f32x4*)&sP[t * 4] = *(const f32x4*)(src + t * 4);
        const int* e = effp + (b * 3 + i) * L;
        i32x4 ev = *(const i32x4*)(e + t * 4);
        #pragma unroll
        for (int k = 0; k < 4; ++k) {
            int id = t * 4 + k;
            sE[(id / 48) * 49 + (id % 48)] = ev[k];
        }
    }
    __syncthreads();

    int y = t / 12, x0 = (t % 12) * 4;     // 576 threads cover 48x12 quads of 4 px
    float s0 = 0.f, s1 = 0.f, s2 = 0.f, s3 = 0.f;
    #pragma unroll
    for (int dh = -1; dh <= 1; ++dh) {
        int ho = y + dh;
        if ((unsigned)ho >= 48u) continue;
        int ep6[6];
        #pragma unroll
        for (int j = 0; j < 6; ++j) {
            int wo = x0 - 1 + j;
            ep6[j] = ((unsigned)wo < 48u) ? sE[ho * 49 + wo] : -1;
        }
        #pragma unroll
        for (int xi = 0; xi < 4; ++xi) {
            float acc = 0.f;
            #pragma unroll
            for (int dw = -1; dw <= 1; ++dw) {
                int ep = ep6[xi + dw + 1];
                if (ep < 0) continue;
                int yy = (ep >> 8) - dh, xx = (ep & 255) - dw;
                if ((unsigned)yy >= 48u || (unsigned)xx >= 48u) continue;
                acc += sP[yy * W + xx];
            }
            if (xi == 0) s0 += acc; else if (xi == 1) s1 += acc;
            else if (xi == 2) s2 += acc; else s3 += acc;
        }
    }
    const float k = 1.0f / 9.0f;
    nts4(outT + (((size_t)i * BATCH + b) * C3 + c) * (size_t)(W * W) + y * W + x0,
         s0 * k, s1 * k, s2 * k, s3 * k);
}

extern "C" void kernel_launch(void* const* d_in, const int* in_sizes, int n_in,
                              void* d_out, int out_size, void* d_ws, size_t ws_size,
                              hipStream_t stream) {
    const float* lr    = (const float*)d_in[0];
    const float* refsr = (const float*)d_in[1];
    const float* ref1  = (const float*)d_in[2];
    const float* ref2  = (const float*)d_in[3];
    const float* ref3  = (const float*)d_in[4];
    float* out = (float*)d_out;

    float*  R   = (float*)d_ws;                              // B*L*L fp32
    float*  G   = R + (size_t)BATCH * L * L;                 // B*L*L fp32
    __bf16* Khi = (__bf16*)(G + (size_t)BATCH * L * L);      // B*L*GK bf16 each
    __bf16* Klo = Khi + (size_t)BATCH * L * GK;
    __bf16* Qhi = Klo + (size_t)BATCH * L * GK;
    __bf16* Qlo = Qhi + (size_t)BATCH * L * GK;
    float* ssQ4 = (float*)(Qlo + (size_t)BATCH * L * GK);    // 4 * B*L
    float* ssK4 = ssQ4 + 4 * BATCH * L;
    float* rnQ = ssK4 + 4 * BATCH * L;
    float* rnK = rnQ + BATCH * L;
    float* apv = rnK + BATCH * L;                            // B*NSEG*L
    float* pv  = apv + (size_t)BATCH * NSEG * L;             // B*NSEG*3*L
    int*   api = (int*)(pv + (size_t)BATCH * NSEG * 3 * L);  // B*NSEG*L
    int*   pr  = api + (size_t)BATCH * NSEG * L;             // B*NSEG*3*L
    int*   hidx = pr + (size_t)BATCH * NSEG * 3 * L;         // B*L
    int*   effp = hidx + BATCH * L;

    ssq_kernel<<<dim3(18, 8), 256, 0, stream>>>(lr, refsr, ssQ4, ssK4);
    norm_kernel<<<dim3(18, 2), 256, 0, stream>>>(ssQ4, ssK4, rnQ, rnK);
    split_t<<<dim3(36, 4, BATCH * 2), 256, 0, stream>>>(lr, refsr, Qhi, Qlo, Khi, Klo);

    gemm_g<<<dim3(18, 36, BATCH), 256, 0, stream>>>(Khi, Klo, Qhi, Qlo, G);
    stencil_R<<<1152, 576, 0, stream>>>(G, rnK, rnQ, R);

    argmax_part<<<dim3(9, NSEG, BATCH), 256, 0, stream>>>(R, apv, api);
    argmax_merge<<<dim3(9, BATCH), 256, 0, stream>>>(apv, api, hidx);
    top3_part<<<dim3(9, NSEG, BATCH), 256, 0, stream>>>(R, hidx, pv, pr);
    top3_merge<<<dim3(9, BATCH), 256, 0, stream>>>(pv, pr, out, effp);

    fold_t3_lds<<<1536, 576, 0, stream>>>(ref3, effp, out + OFF_T3);
    fold_t2_lds<<<768,  576, 0, stream>>>(ref2, effp, out + OFF_T2);
    fold_t1r<<<1536, 576, 0, stream>>>(ref1, effp, out + OFF_T1);
}